// Round 5
// baseline (170.738 us; speedup 1.0000x reference)
//
#include <hip/hip_runtime.h>
#include <cstdint>
#include <cstddef>

typedef float  f32x4 __attribute__((ext_vector_type(4)));
typedef float  f32x2 __attribute__((ext_vector_type(2)));
typedef short  s16x8 __attribute__((ext_vector_type(8)));
typedef short  s16x4 __attribute__((ext_vector_type(4)));
typedef unsigned int u32x4 __attribute__((ext_vector_type(4)));

#define EPSV 1e-5f

__device__ __forceinline__ float rfl(float v) {
  return __builtin_bit_cast(float, __builtin_amdgcn_readfirstlane(__builtin_bit_cast(int, v)));
}
__device__ __forceinline__ unsigned pk2(float a, float b) {
  unsigned short ua = __builtin_bit_cast(unsigned short, (__bf16)a);
  unsigned short ub = __builtin_bit_cast(unsigned short, (__bf16)b);
  return (unsigned)ua | ((unsigned)ub << 16);
}
__device__ __forceinline__ void gll16(const void* g, void* l) {
  __builtin_amdgcn_global_load_lds((const __attribute__((address_space(1))) unsigned int*)g,
                                   (__attribute__((address_space(3))) unsigned int*)l, 16, 0, 0);
}

// ---------------- kernel F: fold BN-o into Wo, emit bf16 in fragment layout ----------------
__global__ void kF(const float* __restrict__ wo, const float* __restrict__ bo,
                   const float* __restrict__ go, const float* __restrict__ beo,
                   const float* __restrict__ mo, const float* __restrict__ vo,
                   __bf16* __restrict__ wopp, float* __restrict__ co)
{
  const int oc = blockIdx.x;   // 0..511
  const int k  = threadIdx.x;  // 0..511
  float invo = go[oc] * rsqrtf(vo[oc] + EPSV);
  float v = wo[(size_t)oc*512 + k] * invo;
  int mt = oc >> 7, ocl = oc & 127;
  int kt = k >> 6, kk = (k >> 5) & 1, g = (k >> 3) & 3, jj = k & 7;
  size_t dst = (size_t)(mt*8 + kt)*10240 + (size_t)kk*5120 + ocl*40 + g*8 + jj;
  wopp[dst] = (__bf16)v;
  if (k == 0) co[oc] = bo[oc]*invo + beo[oc] - mo[oc]*invo;
}

// ---------------- kernel A: 4 dilated depthwise convs + BN + ReLU + 4x4 mix + BN + ReLU ----
// block = (b, c, half-plane): 576 thr, 48 output rows, 8-col x 1-row per thread.
// LDS = 84-row x 136-col f32 window (45.7 KB) -> 3 blocks/CU (27 waves).
// Horizontal OOB via 20-col zero pads; vertical OOB via h2 range check.
__global__ __launch_bounds__(576, 7) void kA(const float* __restrict__ x,
    const float* __restrict__ wdw, const float* __restrict__ bdw, const float* __restrict__ gdw,
    const float* __restrict__ bedw, const float* __restrict__ mdw, const float* __restrict__ vdw,
    const float* __restrict__ w4, const float* __restrict__ bsc, const float* __restrict__ gsc,
    const float* __restrict__ besc, const float* __restrict__ msc, const float* __restrict__ vsc,
    __bf16* __restrict__ z2s)
{
  __shared__ alignas(16) float sp[84*136];   // 45696 B
  const int tid = threadIdx.x;
  const int bc = blockIdx.x >> 1;
  const int half = blockIdx.x & 1;
  const int b = bc >> 7, c = bc & 127;
  const int h0 = half * 48;
  const int loc0 = h0 - 18;                  // LDS row L <-> global row loc0+L
  const int gstart = half ? 30 : 0;          // staged rows: [gstart, gstart+66)
  const int Lbase  = half ? 0 : 18;

  // uniform folded params (readfirstlane -> SGPRs)
  float wf[4][9], cdwv[4], w4f[4][4], c4v[4];
  #pragma unroll
  for (int i = 0; i < 4; ++i) {
    int idx = i*128 + c;
    float inv = gdw[idx] * rsqrtf(vdw[idx] + EPSV);
    #pragma unroll
    for (int t = 0; t < 9; ++t) wf[i][t] = rfl(wdw[(size_t)idx*9 + t] * inv);
    cdwv[i] = rfl(bdw[idx]*inv + bedw[idx] - mdw[idx]*inv);
  }
  #pragma unroll
  for (int o = 0; o < 4; ++o) {
    float invs = gsc[o] * rsqrtf(vsc[o] + EPSV);
    #pragma unroll
    for (int i = 0; i < 4; ++i) w4f[o][i] = rfl(w4[o*4 + i] * invs);
    c4v[o] = rfl(bsc[o]*invs + besc[o] - msc[o]*invs);
  }

  // zero the horizontal pads once (stage phases only write interior cols 20..115)
  for (int z = tid; z < 84*40; z += 576) {
    int row = z / 40, cw = z - row*40;
    sp[row*136 + (cw < 20 ? cw : 96 + cw)] = 0.f;
  }

  const int colg = tid % 12;            // 12 col-groups of 8
  const int rowt = tid / 12;            // 0..47
  const int h  = h0 + rowt;
  const int w0 = colg * 8;

  const f32x4* xv = (const f32x4*)x;
  const size_t gbase = (size_t)(b*512 + c) * 2304;   // f32x4 units; +i*294912 per branch

  float zacc[4][8];
  #pragma unroll
  for (int o = 0; o < 4; ++o)
    #pragma unroll
    for (int j = 0; j < 8; ++j) zacc[o][j] = c4v[o];

  #pragma unroll
  for (int i = 0; i < 4; ++i) {
    __syncthreads();   // i=0: pads visible; i>0: prior compute done with buffer
    for (int idx = tid; idx < 1584; idx += 576) {      // 66 rows x 24 f32x4
      int rr = idx / 24, cc = idx - rr*24;
      f32x4 v = xv[gbase + (size_t)i*294912 + (size_t)(gstart + rr)*24 + cc];
      *(f32x4*)(sp + (Lbase + rr)*136 + 20 + cc*4) = v;
    }
    __syncthreads();

    const int r = (i == 0) ? 1 : (i == 1) ? 6 : (i == 2) ? 12 : 18;
    float acc[8];
    #pragma unroll
    for (int j = 0; j < 8; ++j) acc[j] = 0.f;

    #pragma unroll
    for (int dh = -1; dh <= 1; ++dh) {
      const int h2 = h + dh*r;
      if ((unsigned)h2 < 96u) {
        const float* row = sp + (h2 - loc0)*136 + 20 + w0;
        const float wl = wf[i][(dh+1)*3], wc = wf[i][(dh+1)*3+1], wr = wf[i][(dh+1)*3+2];
        if (i == 0) {            // r=1: span [w0-2, w0+10) = 6 b64; tl=s[j+1] tc=s[j+2] tr=s[j+3]
          float s[12];
          #pragma unroll
          for (int t = 0; t < 6; ++t) *(f32x2*)(s + 2*t) = *(const f32x2*)(row - 2 + 2*t);
          #pragma unroll
          for (int j = 0; j < 8; ++j)
            acc[j] += wl*s[j+1] + wc*s[j+2] + wr*s[j+3];
        } else if (i == 1) {     // r=6: span [w0-6, w0+14) = 10 b64; tl=s[j] tc=s[j+6] tr=s[j+12]
          float s[20];
          #pragma unroll
          for (int t = 0; t < 10; ++t) *(f32x2*)(s + 2*t) = *(const f32x2*)(row - 6 + 2*t);
          #pragma unroll
          for (int j = 0; j < 8; ++j)
            acc[j] += wl*s[j] + wc*s[j+6] + wr*s[j+12];
        } else if (i == 2) {     // r=12: aligned taps, 6 b128
          float tl[8], tc[8], tr[8];
          *(f32x4*)(tl)   = *(const f32x4*)(row - 12); *(f32x4*)(tl+4) = *(const f32x4*)(row - 8);
          *(f32x4*)(tc)   = *(const f32x4*)(row);      *(f32x4*)(tc+4) = *(const f32x4*)(row + 4);
          *(f32x4*)(tr)   = *(const f32x4*)(row + 12); *(f32x4*)(tr+4) = *(const f32x4*)(row + 16);
          #pragma unroll
          for (int j = 0; j < 8; ++j)
            acc[j] += wl*tl[j] + wc*tc[j] + wr*tr[j];
        } else {                 // r=18: tl 4 b64, tc 2 b128, tr 4 b64
          float tl[8], tc[8], tr[8];
          #pragma unroll
          for (int t = 0; t < 4; ++t) *(f32x2*)(tl + 2*t) = *(const f32x2*)(row - 18 + 2*t);
          *(f32x4*)(tc)   = *(const f32x4*)(row);      *(f32x4*)(tc+4) = *(const f32x4*)(row + 4);
          #pragma unroll
          for (int t = 0; t < 4; ++t) *(f32x2*)(tr + 2*t) = *(const f32x2*)(row + 18 + 2*t);
          #pragma unroll
          for (int j = 0; j < 8; ++j)
            acc[j] += wl*tl[j] + wc*tc[j] + wr*tr[j];
        }
      }
    }
    #pragma unroll
    for (int j = 0; j < 8; ++j) {
      float y = fmaxf(acc[j] + cdwv[i], 0.f);
      #pragma unroll
      for (int o = 0; o < 4; ++o) zacc[o][j] += w4f[o][i]*y;
    }
  }

  // finalize + store: [pix][o]; thread owns quads q0, q0+1 -> 64B contiguous
  float z0[8], z1[8], z2[8], z3[8];
  #pragma unroll
  for (int j = 0; j < 8; ++j) {
    z0[j] = fmaxf(zacc[0][j], 0.f);
    z1[j] = fmaxf(zacc[1][j], 0.f);
    z2[j] = fmaxf(zacc[2][j], 0.f);
    z3[j] = fmaxf(zacc[3][j], 0.f);
  }
  __bf16* zb = z2s + (size_t)(b*128 + c)*36864 + (size_t)(h*24 + colg*2)*16;
  u32x4* dst = (u32x4*)zb;
  u32x4 s0 = { pk2(z0[0],z1[0]), pk2(z2[0],z3[0]), pk2(z0[1],z1[1]), pk2(z2[1],z3[1]) };
  u32x4 s1 = { pk2(z0[2],z1[2]), pk2(z2[2],z3[2]), pk2(z0[3],z1[3]), pk2(z2[3],z3[3]) };
  u32x4 s2 = { pk2(z0[4],z1[4]), pk2(z2[4],z3[4]), pk2(z0[5],z1[5]), pk2(z2[5],z3[5]) };
  u32x4 s3 = { pk2(z0[6],z1[6]), pk2(z2[6],z3[6]), pk2(z0[7],z1[7]), pk2(z2[7],z3[7]) };
  dst[0] = s0; dst[1] = s1; dst[2] = s2; dst[3] = s3;
}

// ---------------- kernel B: out = ReLU(Wo'' @ z2 + co), bf16 MFMA, m97 structure -----------
__global__ __launch_bounds__(256) void kB(const void* __restrict__ wopp_,
    const void* __restrict__ z2s_, const float* __restrict__ co, float* __restrict__ out)
{
  __shared__ alignas(16) char lA[20480];
  __shared__ alignas(16) char lB[16384];
  const char* wopp = (const char*)wopp_;
  const char* z2s  = (const char*)z2s_;

  const int tid = threadIdx.x;
  const int lane = tid & 63, wv = tid >> 6;
  const int wm = wv >> 1, wn = wv & 1;
  const int pt = blockIdx.x;      // 0..71 pixel tiles
  const int mt = blockIdx.y;      // 0..3  oc tiles
  const int b  = blockIdx.z;      // 0..7
  const int pix0 = pt * 128;
  const int l15 = lane & 15, lg = lane >> 4;

  f32x4 acc[4][4] = {};

  for (int kt = 0; kt < 8; ++kt) {
    const char* srcA = wopp + (size_t)(mt*8 + kt)*20480;
    for (int j = wv; j < 20; j += 4)
      gll16(srcA + j*1024 + lane*16, lA + j*1024);
    #pragma unroll
    for (int ct4 = 0; ct4 < 4; ++ct4) {
      int ct = wv*4 + ct4;
      const char* srcB = z2s + ((size_t)(b*128 + kt*16 + ct)*36864 + (size_t)pix0*4)*2;
      gll16(srcB + lane*16, lB + ct*1024);
    }
    __syncthreads();

    #pragma unroll
    for (int kk = 0; kk < 2; ++kk) {
      s16x8 af[4];
      #pragma unroll
      for (int m = 0; m < 4; ++m)
        af[m] = *(const s16x8*)(lA + kk*10240 + (wm*64 + m*16 + l15)*80 + lg*16);
      #pragma unroll
      for (int n = 0; n < 4; ++n) {
        const char* p = lB + kk*8192 + lg*2048 + (wn*64 + n*16 + l15)*8;
        s16x4 lo = *(const s16x4*)(p);
        s16x4 hi = *(const s16x4*)(p + 1024);
        s16x8 bfr = __builtin_shufflevector(lo, hi, 0,1,2,3,4,5,6,7);
        #pragma unroll
        for (int m = 0; m < 4; ++m)
          acc[m][n] = __builtin_amdgcn_mfma_f32_16x16x32_bf16(af[m], bfr, acc[m][n], 0, 0, 0);
      }
    }
    __syncthreads();
  }

  const int colp = pix0 + wn*64 + l15;
  #pragma unroll
  for (int m = 0; m < 4; ++m) {
    const int ocb = mt*128 + wm*64 + m*16 + lg*4;
    #pragma unroll
    for (int r2 = 0; r2 < 4; ++r2) {
      const int oc = ocb + r2;
      const float cov = co[oc];
      float* orow = out + ((size_t)(b*512 + oc))*9216 + colp;
      #pragma unroll
      for (int n = 0; n < 4; ++n) {
        float v = acc[m][n][r2] + cov;
        orow[(size_t)n*16] = fmaxf(v, 0.f);
      }
    }
  }
}

extern "C" void kernel_launch(void* const* d_in, const int* in_sizes, int n_in,
                              void* d_out, int out_size, void* d_ws, size_t ws_size,
                              hipStream_t stream)
{
  (void)in_sizes; (void)out_size;
  if (n_in < 19) return;
  const size_t Z2_BYTES = 75497472;      // 8*512*9216 bf16
  const size_t WOPP_BYTES = 655360;      // 32 chunks * 20480
  if (ws_size < Z2_BYTES + WOPP_BYTES + 2048) return;

  const float* x    = (const float*)d_in[0];
  const float* wdw  = (const float*)d_in[1];
  const float* bdw  = (const float*)d_in[2];
  const float* gdw  = (const float*)d_in[3];
  const float* bedw = (const float*)d_in[4];
  const float* mdw  = (const float*)d_in[5];
  const float* vdw  = (const float*)d_in[6];
  const float* w4   = (const float*)d_in[7];
  const float* bs   = (const float*)d_in[8];
  const float* gs   = (const float*)d_in[9];
  const float* bes  = (const float*)d_in[10];
  const float* ms   = (const float*)d_in[11];
  const float* vs   = (const float*)d_in[12];
  const float* wo   = (const float*)d_in[13];
  const float* bo   = (const float*)d_in[14];
  const float* go   = (const float*)d_in[15];
  const float* beo  = (const float*)d_in[16];
  const float* mo   = (const float*)d_in[17];
  const float* vo   = (const float*)d_in[18];

  __bf16* z2s  = (__bf16*)d_ws;
  __bf16* wopp = (__bf16*)((char*)d_ws + Z2_BYTES);
  float*  co   = (float*)((char*)d_ws + Z2_BYTES + WOPP_BYTES);

  kF<<<512, 512, 0, stream>>>(wo, bo, go, beo, mo, vo, wopp, co);
  kA<<<2048, 576, 0, stream>>>(x, wdw, bdw, gdw, bedw, mdw, vdw, w4, bs, gs, bes, ms, vs, z2s);
  kB<<<dim3(72, 4, 8), 256, 0, stream>>>(wopp, z2s, co, (float*)d_out);
}